// Round 3
// baseline (878.562 us; speedup 1.0000x reference)
//
#include <hip/hip_runtime.h>
#include <hip/hip_bf16.h>
#include <stdint.h>

// ---------------- problem dims ----------------
#define BTOT   65536
#define DIN    784
#define K1P    800     // layer-1 K padded: 784 data + bias row @784 + zeros
#define NH1    256
#define K2P    288     // layer-2/gate K padded: 256 data + bias row @256 + zeros
#define NH2    64
#define NEXP   10
#define BM     64
#define NKS1   25      // 800/32
#define NKS2   9       // 288/32

// ---------------- LDS layout ----------------
#define XSTRIDE 808
#define HSTRIDE 296
#define H_OFF    (BM * XSTRIDE * 2)            // 103424
#define EXP_OFF  (H_OFF + BM * HSTRIDE * 2)    // 141312
#define W3_OFF   (EXP_OFF + BM * NEXP * 4)     // 143872
#define B3_OFF   (W3_OFF + NEXP * NH2 * 4)     // 146432
#define LDS_TOTAL (B3_OFF + 64)                // 146496

typedef short s16x8 __attribute__((ext_vector_type(8)));
typedef float f32x4 __attribute__((ext_vector_type(4)));

// ---------------- prep: transpose + bf16 + bias-fold into ws ----------------
__global__ void prep_w1(const float* __restrict__ W1, const float* __restrict__ b1,
                        const float* __restrict__ Wg1, const float* __restrict__ bg1,
                        __bf16* __restrict__ dst) {
    int t = blockIdx.x * 256 + threadIdx.x;
    if (t >= 11 * 64 * K1P) return;
    int k  = t % K1P;
    int n4 = (t / K1P) & 63;
    int e  = t / (K1P * 64);
    float4 v = {0.f, 0.f, 0.f, 0.f};
    if (k < DIN) {
        const float* src = (e < NEXP) ? (W1 + ((size_t)e * DIN + k) * NH1)
                                      : (Wg1 + (size_t)k * NH1);
        v = *(const float4*)(src + n4 * 4);
    } else if (k == DIN) {
        const float* src = (e < NEXP) ? (b1 + e * NH1) : bg1;
        v = *(const float4*)(src + n4 * 4);
    }
    size_t base = ((size_t)e * NH1 + n4 * 4) * K1P + k;
    dst[base]           = (__bf16)v.x;
    dst[base + K1P]     = (__bf16)v.y;
    dst[base + 2 * K1P] = (__bf16)v.z;
    dst[base + 3 * K1P] = (__bf16)v.w;
}

__global__ void prep_w2(const float* __restrict__ W2, const float* __restrict__ b2,
                        __bf16* __restrict__ dst) {
    int t = blockIdx.x * 256 + threadIdx.x;
    if (t >= 10 * 16 * K2P) return;
    int k  = t % K2P;
    int j4 = (t / K2P) & 15;
    int e  = t / (K2P * 16);
    float4 v = {0.f, 0.f, 0.f, 0.f};
    if (k < NH1)       v = *(const float4*)(W2 + ((size_t)e * NH1 + k) * NH2 + j4 * 4);
    else if (k == NH1) v = *(const float4*)(b2 + e * NH2 + j4 * 4);
    size_t base = ((size_t)e * NH2 + j4 * 4) * K2P + k;
    dst[base]           = (__bf16)v.x;
    dst[base + K2P]     = (__bf16)v.y;
    dst[base + 2 * K2P] = (__bf16)v.z;
    dst[base + 3 * K2P] = (__bf16)v.w;
}

__global__ void prep_wg2(const float* __restrict__ Wg2, const float* __restrict__ bg2,
                         __bf16* __restrict__ dst) {
    int t = blockIdx.x * 256 + threadIdx.x;
    if (t >= 16 * K2P) return;
    int k = t % K2P;
    int j = t / K2P;
    float v = 0.f;
    if (j < NEXP) {
        if (k < NH1)       v = Wg2[(size_t)k * NEXP + j];
        else if (k == NH1) v = bg2[j];
    }
    dst[(size_t)j * K2P + k] = (__bf16)v;
}

// ---------------- fused MoE kernel ----------------
// 4 waves, 64 rows/block, x LDS-resident. Weights stream global->reg with a
// 4-deep rotating register pipeline (~16 b128 in flight/wave); x frags 2-deep
// from LDS. Expert e+1's first 4 weight K-tiles are issued before the h-write
// barrier so their latency hides under epilogue+layer-2.
__global__ void __launch_bounds__(256, 1)
moe_fused(const float* __restrict__ x, const float* __restrict__ W3,
          const float* __restrict__ b3, const __bf16* __restrict__ w1t,
          const __bf16* __restrict__ w2t, const __bf16* __restrict__ wg2t,
          float* __restrict__ out)
{
    extern __shared__ char lds[];
    __bf16* xs   = (__bf16*)lds;
    __bf16* h    = (__bf16*)(lds + H_OFF);
    float*  expl = (float*)(lds + EXP_OFF);
    float*  w3s  = (float*)(lds + W3_OFF);
    float*  b3s  = (float*)(lds + B3_OFF);

    const int tid  = threadIdx.x;
    const int lane = tid & 63;
    const int wave = tid >> 6;
    const int lr   = lane & 15;
    const int lg   = lane >> 4;
    const int row0 = blockIdx.x * BM;
    const f32x4 fz = {0.f, 0.f, 0.f, 0.f};

    // ---- stage x tile fp32->bf16 (once) + constants ----
    {
        const float* xg = x + (size_t)row0 * DIN;
        #pragma unroll 4
        for (int i = 0; i < 49; ++i) {               // 49*256 == 64*196
            int idx = tid + i * 256;
            int r = idx / 196, c = (idx % 196) * 4;
            float4 v = *(const float4*)(xg + (size_t)r * DIN + c);
            uint2 w; __bf16* p = (__bf16*)&w;
            p[0] = (__bf16)v.x; p[1] = (__bf16)v.y;
            p[2] = (__bf16)v.z; p[3] = (__bf16)v.w;
            *(uint2*)(xs + r * XSTRIDE + c) = w;
        }
        for (int i = tid; i < 64 * 16; i += 256) {   // cols 784..799: 1.0 then 0
            int r = i >> 4, c = DIN + (i & 15);
            xs[r * XSTRIDE + c] = (c == DIN) ? (__bf16)1.f : (__bf16)0.f;
        }
        for (int i = tid; i < 64 * 32; i += 256) {   // h cols 256..287 (constant)
            int r = i >> 5, c = NH1 + (i & 31);
            h[r * HSTRIDE + c] = (c == NH1) ? (__bf16)1.f : (__bf16)0.f;
        }
        for (int i = tid; i < NEXP * NH2; i += 256) w3s[i] = W3[i];
        if (tid < NEXP) b3s[tid] = b3[tid];
    }
    __syncthreads();

    // ---- weight pipeline prologue for expert 0 ----
    s16x8 w[4][4];
    {
        const __bf16* w1e = w1t + ((size_t)(wave * 64 + lr)) * K1P + lg * 8;
        #pragma unroll
        for (int p = 0; p < 4; ++p)
            #pragma unroll
            for (int nt = 0; nt < 4; ++nt)
                w[p][nt] = *(const s16x8*)(w1e + (size_t)nt * 16 * K1P + p * 32);
    }

    for (int e = 0; e <= NEXP; ++e) {
        const __bf16* w1e = w1t + ((size_t)e * NH1 + wave * 64 + lr) * K1P + lg * 8;

        // x-frag prologue (2-deep from LDS)
        s16x8 a[2][4];
        #pragma unroll
        for (int p = 0; p < 2; ++p)
            #pragma unroll
            for (int mt = 0; mt < 4; ++mt)
                a[p][mt] = *(const s16x8*)(xs + (mt * 16 + lr) * XSTRIDE + p * 32 + lg * 8);

        f32x4 acc[4][4];
        #pragma unroll
        for (int nt = 0; nt < 4; ++nt)
            #pragma unroll
            for (int mt = 0; mt < 4; ++mt) acc[nt][mt] = fz;

        // ---- fully-unrolled 25-step K loop, rotating buffers ----
        #pragma unroll
        for (int t = 0; t < NKS1; ++t) {
            const int cw = t & 3, ca = t & 1;
            #pragma unroll
            for (int nt = 0; nt < 4; ++nt)
                #pragma unroll
                for (int mt = 0; mt < 4; ++mt)
                    acc[nt][mt] = __builtin_amdgcn_mfma_f32_16x16x32_bf16(
                        w[cw][nt], a[ca][mt], acc[nt][mt], 0, 0, 0);
            if (t + 2 < NKS1) {
                #pragma unroll
                for (int mt = 0; mt < 4; ++mt)
                    a[ca][mt] = *(const s16x8*)(xs + (mt * 16 + lr) * XSTRIDE
                                                + (t + 2) * 32 + lg * 8);
            }
            if (t + 4 < NKS1) {
                #pragma unroll
                for (int nt = 0; nt < 4; ++nt)
                    w[cw][nt] = *(const s16x8*)(w1e + (size_t)nt * 16 * K1P
                                                + (t + 4) * 32);
            }
        }

        // issue expert e+1's first 4 K-tiles now: latency hides under
        // h-write + barriers + layer-2
        if (e < NEXP) {
            const __bf16* w1n = w1e + (size_t)NH1 * K1P;
            #pragma unroll
            for (int p = 0; p < 4; ++p)
                #pragma unroll
                for (int nt = 0; nt < 4; ++nt)
                    w[p][nt] = *(const s16x8*)(w1n + (size_t)nt * 16 * K1P + p * 32);
        }

        __syncthreads();   // (1) all waves done reading previous h
        // h[m][n] = relu(acc):  (nt,mt,r) -> C[m=mt*16+lr][n=wave*64+nt*16+lg*4+r]
        #pragma unroll
        for (int mt = 0; mt < 4; ++mt)
            #pragma unroll
            for (int nt = 0; nt < 4; ++nt) {
                uint2 wv; __bf16* p = (__bf16*)&wv;
                #pragma unroll
                for (int r = 0; r < 4; ++r)
                    p[r] = (__bf16)fmaxf(acc[nt][mt][r], 0.f);
                *(uint2*)(h + (mt * 16 + lr) * HSTRIDE + wave * 64 + nt * 16 + lg * 4) = wv;
            }
        __syncthreads();   // (2) h ready

        if (e < NEXP) {
            // ================= layer 2 (depth-3 weights, depth-2 h frags) =====
            const __bf16* w2e = w2t + ((size_t)e * NH2 + lr) * K2P + lg * 8;
            const __bf16* hrow = h + (wave * 16 + lr) * HSTRIDE + lg * 8;
            s16x8 v[3][4], hf[2];
            #pragma unroll
            for (int p = 0; p < 3; ++p)
                #pragma unroll
                for (int jt = 0; jt < 4; ++jt)
                    v[p][jt] = *(const s16x8*)(w2e + (size_t)jt * 16 * K2P + p * 32);
            #pragma unroll
            for (int p = 0; p < 2; ++p)
                hf[p] = *(const s16x8*)(hrow + p * 32);

            f32x4 acc2[4];
            #pragma unroll
            for (int jt = 0; jt < 4; ++jt) acc2[jt] = fz;

            #pragma unroll
            for (int t = 0; t < NKS2; ++t) {
                const int cw = t % 3, ca = t & 1;
                #pragma unroll
                for (int jt = 0; jt < 4; ++jt)
                    acc2[jt] = __builtin_amdgcn_mfma_f32_16x16x32_bf16(
                        v[cw][jt], hf[ca], acc2[jt], 0, 0, 0);
                if (t + 2 < NKS2)
                    hf[ca] = *(const s16x8*)(hrow + (t + 2) * 32);
                if (t + 3 < NKS2) {
                    #pragma unroll
                    for (int jt = 0; jt < 4; ++jt)
                        v[cw][jt] = *(const s16x8*)(w2e + (size_t)jt * 16 * K2P
                                                    + (t + 3) * 32);
                }
            }
            // ---- layer 3: lane owns m = wave*16+lr, j = jt*16+lg*4+r ----
            float part = 0.f;
            const float* w3e = w3s + e * NH2 + lg * 4;
            #pragma unroll
            for (int jt = 0; jt < 4; ++jt) {
                f32x4 w3v = *(const f32x4*)(w3e + jt * 16);
                #pragma unroll
                for (int r = 0; r < 4; ++r)
                    part += fmaxf(acc2[jt][r], 0.f) * w3v[r];
            }
            part += __shfl_xor(part, 16, 64);
            part += __shfl_xor(part, 32, 64);
            if (lane < 16)
                expl[(wave * 16 + lane) * NEXP + e] = part + b3s[e];
        } else {
            // ================= gate: logits -> softmax -> combine =============
            const __bf16* wge = wg2t + (size_t)lr * K2P + lg * 8;
            const __bf16* hrow = h + (wave * 16 + lr) * HSTRIDE + lg * 8;
            s16x8 gf[2], hf[2];
            #pragma unroll
            for (int p = 0; p < 2; ++p) {
                gf[p] = *(const s16x8*)(wge + p * 32);
                hf[p] = *(const s16x8*)(hrow + p * 32);
            }
            f32x4 acc3 = fz;
            #pragma unroll
            for (int t = 0; t < NKS2; ++t) {
                const int ca = t & 1;
                acc3 = __builtin_amdgcn_mfma_f32_16x16x32_bf16(gf[ca], hf[ca], acc3, 0, 0, 0);
                if (t + 2 < NKS2) {
                    gf[ca] = *(const s16x8*)(wge + (t + 2) * 32);
                    hf[ca] = *(const s16x8*)(hrow + (t + 2) * 32);
                }
            }
            // lane: m = wave*16+lr, expert ep = lg*4+r
            const int m = wave * 16 + lr;
            float lv[4], mx = -1e30f;
            #pragma unroll
            for (int r = 0; r < 4; ++r) {
                int ep = lg * 4 + r;
                lv[r] = (ep < NEXP) ? acc3[r] : -1e30f;
                mx = fmaxf(mx, lv[r]);
            }
            mx = fmaxf(mx, __shfl_xor(mx, 16, 64));
            mx = fmaxf(mx, __shfl_xor(mx, 32, 64));
            float p[4], s = 0.f;
            #pragma unroll
            for (int r = 0; r < 4; ++r) {
                int ep = lg * 4 + r;
                p[r] = (ep < NEXP) ? __expf(lv[r] - mx) : 0.f;
                s += p[r];
            }
            s += __shfl_xor(s, 16, 64);
            s += __shfl_xor(s, 32, 64);
            #pragma unroll
            for (int r = 0; r < 4; ++r) {
                int ep = lg * 4 + r;
                if (ep < NEXP) {
                    float g  = p[r] / s;
                    float eo = expl[m * NEXP + ep];
                    size_t o = (size_t)(row0 + m) * NEXP + ep;
                    out[o] = g * eo;                        // output
                    out[(size_t)BTOT * NEXP + o] = g;       // gate_scores
                    out[(size_t)2 * BTOT * NEXP + o] = eo;  // expert_outputs
                }
            }
        }
    }
}

extern "C" void kernel_launch(void* const* d_in, const int* in_sizes, int n_in,
                              void* d_out, int out_size, void* d_ws, size_t ws_size,
                              hipStream_t stream) {
    (void)in_sizes; (void)n_in; (void)out_size; (void)ws_size;
    const float* x   = (const float*)d_in[0];
    const float* W1  = (const float*)d_in[1];
    const float* b1  = (const float*)d_in[2];
    const float* W2  = (const float*)d_in[3];
    const float* b2  = (const float*)d_in[4];
    const float* W3  = (const float*)d_in[5];
    const float* b3  = (const float*)d_in[6];
    const float* Wg1 = (const float*)d_in[7];
    const float* bg1 = (const float*)d_in[8];
    const float* Wg2 = (const float*)d_in[9];
    const float* bg2 = (const float*)d_in[10];

    // ws (bf16): w1t [11][256][800] | w2t [10][64][288] | wg2t [16][288]
    __bf16* w1t  = (__bf16*)d_ws;
    __bf16* w2t  = w1t + (size_t)11 * NH1 * K1P;
    __bf16* wg2t = w2t + (size_t)10 * NH2 * K2P;

    hipFuncSetAttribute((const void*)moe_fused,
                        hipFuncAttributeMaxDynamicSharedMemorySize, LDS_TOTAL);

    prep_w1<<<(11 * 64 * K1P + 255) / 256, 256, 0, stream>>>(W1, b1, Wg1, bg1, w1t);
    prep_w2<<<(10 * 16 * K2P + 255) / 256, 256, 0, stream>>>(W2, b2, w2t);
    prep_wg2<<<(16 * K2P + 255) / 256, 256, 0, stream>>>(Wg2, bg2, wg2t);
    moe_fused<<<BTOT / BM, 256, LDS_TOTAL, stream>>>(x, W3, b3, w1t, w2t, wg2t,
                                                     (float*)d_out);
}

// Round 4
// 487.091 us; speedup vs baseline: 1.8037x; 1.8037x over previous
//
#include <hip/hip_runtime.h>
#include <hip/hip_bf16.h>
#include <stdint.h>

// ---------------- problem dims ----------------
#define BTOT   65536
#define DIN    784
#define K1P    800     // layer-1 K padded: 784 data + bias row @784 + zeros
#define NH1    256
#define K2P    288     // layer-2/gate K padded: 256 data + bias row @256 + zeros
#define NH2    64
#define NEXP   10
#define BM     64
#define NKS1   25      // 800/32
#define NKS2   9       // 288/32

// ---------------- LDS layout ----------------
#define XSTRIDE 808
#define HSTRIDE 296
#define H_OFF    (BM * XSTRIDE * 2)            // 103424
#define EXP_OFF  (H_OFF + BM * HSTRIDE * 2)    // 141312
#define W3_OFF   (EXP_OFF + BM * NEXP * 4)     // 143872
#define B3_OFF   (W3_OFF + NEXP * NH2 * 4)     // 146432
#define LDS_TOTAL (B3_OFF + 64)                // 146496

typedef short s16x8 __attribute__((ext_vector_type(8)));
typedef float f32x4 __attribute__((ext_vector_type(4)));

// ---------------- prep: transpose + bf16 + bias-fold into ws ----------------
__global__ void prep_w1(const float* __restrict__ W1, const float* __restrict__ b1,
                        const float* __restrict__ Wg1, const float* __restrict__ bg1,
                        __bf16* __restrict__ dst) {
    int t = blockIdx.x * 256 + threadIdx.x;
    if (t >= 11 * 64 * K1P) return;
    int k  = t % K1P;
    int n4 = (t / K1P) & 63;
    int e  = t / (K1P * 64);
    float4 v = {0.f, 0.f, 0.f, 0.f};
    if (k < DIN) {
        const float* src = (e < NEXP) ? (W1 + ((size_t)e * DIN + k) * NH1)
                                      : (Wg1 + (size_t)k * NH1);
        v = *(const float4*)(src + n4 * 4);
    } else if (k == DIN) {
        const float* src = (e < NEXP) ? (b1 + e * NH1) : bg1;
        v = *(const float4*)(src + n4 * 4);
    }
    size_t base = ((size_t)e * NH1 + n4 * 4) * K1P + k;
    dst[base]           = (__bf16)v.x;
    dst[base + K1P]     = (__bf16)v.y;
    dst[base + 2 * K1P] = (__bf16)v.z;
    dst[base + 3 * K1P] = (__bf16)v.w;
}

__global__ void prep_w2(const float* __restrict__ W2, const float* __restrict__ b2,
                        __bf16* __restrict__ dst) {
    int t = blockIdx.x * 256 + threadIdx.x;
    if (t >= 10 * 16 * K2P) return;
    int k  = t % K2P;
    int j4 = (t / K2P) & 15;
    int e  = t / (K2P * 16);
    float4 v = {0.f, 0.f, 0.f, 0.f};
    if (k < NH1)       v = *(const float4*)(W2 + ((size_t)e * NH1 + k) * NH2 + j4 * 4);
    else if (k == NH1) v = *(const float4*)(b2 + e * NH2 + j4 * 4);
    size_t base = ((size_t)e * NH2 + j4 * 4) * K2P + k;
    dst[base]           = (__bf16)v.x;
    dst[base + K2P]     = (__bf16)v.y;
    dst[base + 2 * K2P] = (__bf16)v.z;
    dst[base + 3 * K2P] = (__bf16)v.w;
}

__global__ void prep_wg2(const float* __restrict__ Wg2, const float* __restrict__ bg2,
                         __bf16* __restrict__ dst) {
    int t = blockIdx.x * 256 + threadIdx.x;
    if (t >= 16 * K2P) return;
    int k = t % K2P;
    int j = t / K2P;
    float v = 0.f;
    if (j < NEXP) {
        if (k < NH1)       v = Wg2[(size_t)k * NEXP + j];
        else if (k == NH1) v = bg2[j];
    }
    dst[(size_t)j * K2P + k] = (__bf16)v;
}

// ---- macro bodies: slot index S is a LITERAL -> arrays stay in registers ----
#define L1_MMA(S)                                                             \
    {                                                                         \
        _Pragma("unroll") for (int nt = 0; nt < 4; ++nt)                      \
            _Pragma("unroll") for (int mt = 0; mt < 4; ++mt)                  \
                acc[nt][mt] = __builtin_amdgcn_mfma_f32_16x16x32_bf16(        \
                    w[S][nt], a[S][mt], acc[nt][mt], 0, 0, 0);                \
    }

#define L1_PF(S, TNEXT)                                                       \
    {                                                                         \
        _Pragma("unroll") for (int mt = 0; mt < 4; ++mt)                      \
            a[S][mt] = *(const s16x8*)(xs + (mt * 16 + lr) * XSTRIDE          \
                                       + (TNEXT) * 32 + lg * 8);              \
        _Pragma("unroll") for (int nt = 0; nt < 4; ++nt)                      \
            w[S][nt] = *(const s16x8*)(w1e + (size_t)nt * 16 * K1P            \
                                       + (TNEXT) * 32);                       \
    }

#define L2_MMA(S)                                                             \
    {                                                                         \
        _Pragma("unroll") for (int jt = 0; jt < 4; ++jt)                      \
            acc2[jt] = __builtin_amdgcn_mfma_f32_16x16x32_bf16(               \
                v[S][jt], hf[S], acc2[jt], 0, 0, 0);                          \
    }

#define L2_PF(S, TNEXT)                                                       \
    {                                                                         \
        hf[S] = *(const s16x8*)(hrow + (TNEXT) * 32);                         \
        _Pragma("unroll") for (int jt = 0; jt < 4; ++jt)                      \
            v[S][jt] = *(const s16x8*)(w2e + (size_t)jt * 16 * K2P            \
                                       + (TNEXT) * 32);                       \
    }

// ---------------- fused MoE kernel ----------------
// 4 waves, 64 rows/block, x LDS-resident. Weights stream global->reg through
// 3-deep rotating register slots inside a ROLLED macro-loop (statically
// indexed -> no scratch, compiler can't collapse the pipeline). Next-expert
// and layer-2 weight slots are issued before the barrier so the barrier
// drain pays their latency under the epilogue.
__global__ void __launch_bounds__(256, 1)
moe_fused(const float* __restrict__ x, const float* __restrict__ W3,
          const float* __restrict__ b3, const __bf16* __restrict__ w1t,
          const __bf16* __restrict__ w2t, const __bf16* __restrict__ wg2t,
          float* __restrict__ out)
{
    extern __shared__ char lds[];
    __bf16* xs   = (__bf16*)lds;
    __bf16* h    = (__bf16*)(lds + H_OFF);
    float*  expl = (float*)(lds + EXP_OFF);
    float*  w3s  = (float*)(lds + W3_OFF);
    float*  b3s  = (float*)(lds + B3_OFF);

    const int tid  = threadIdx.x;
    const int lane = tid & 63;
    const int wave = tid >> 6;
    const int lr   = lane & 15;
    const int lg   = lane >> 4;
    const int row0 = blockIdx.x * BM;
    const f32x4 fz = {0.f, 0.f, 0.f, 0.f};

    // ---- issue expert-0 weight slots FIRST (latency hides under x-staging) ----
    s16x8 w[3][4], a[3][4];
    {
        const __bf16* w1e = w1t + ((size_t)(wave * 64 + lr)) * K1P + lg * 8;
        #pragma unroll
        for (int p = 0; p < 3; ++p)
            #pragma unroll
            for (int nt = 0; nt < 4; ++nt)
                w[p][nt] = *(const s16x8*)(w1e + (size_t)nt * 16 * K1P + p * 32);
    }

    // ---- stage x tile fp32->bf16 (once) + constants ----
    {
        const float* xg = x + (size_t)row0 * DIN;
        #pragma unroll 4
        for (int i = 0; i < 49; ++i) {               // 49*256 == 64*196
            int idx = tid + i * 256;
            int r = idx / 196, c = (idx % 196) * 4;
            float4 v = *(const float4*)(xg + (size_t)r * DIN + c);
            uint2 wv; __bf16* p = (__bf16*)&wv;
            p[0] = (__bf16)v.x; p[1] = (__bf16)v.y;
            p[2] = (__bf16)v.z; p[3] = (__bf16)v.w;
            *(uint2*)(xs + r * XSTRIDE + c) = wv;
        }
        for (int i = tid; i < 64 * 16; i += 256) {   // cols 784..799: 1.0 then 0
            int r = i >> 4, c = DIN + (i & 15);
            xs[r * XSTRIDE + c] = (c == DIN) ? (__bf16)1.f : (__bf16)0.f;
        }
        for (int i = tid; i < 64 * 32; i += 256) {   // h cols 256..287 (constant)
            int r = i >> 5, c = NH1 + (i & 31);
            h[r * HSTRIDE + c] = (c == NH1) ? (__bf16)1.f : (__bf16)0.f;
        }
        for (int i = tid; i < NEXP * NH2; i += 256) w3s[i] = W3[i];
        if (tid < NEXP) b3s[tid] = b3[tid];
    }
    __syncthreads();

    // a-slot prologue for expert 0
    #pragma unroll
    for (int p = 0; p < 3; ++p)
        #pragma unroll
        for (int mt = 0; mt < 4; ++mt)
            a[p][mt] = *(const s16x8*)(xs + (mt * 16 + lr) * XSTRIDE + p * 32 + lg * 8);

    for (int e = 0; e <= NEXP; ++e) {
        const __bf16* w1e = w1t + ((size_t)e * NH1 + wave * 64 + lr) * K1P + lg * 8;
        const __bf16* w2e = w2t + ((size_t)e * NH2 + lr) * K2P + lg * 8;

        f32x4 acc[4][4];
        #pragma unroll
        for (int nt = 0; nt < 4; ++nt)
            #pragma unroll
            for (int mt = 0; mt < 4; ++mt) acc[nt][mt] = fz;

        // ---- K loop: rolled, 3 static slot-bodies per iter, depth-3 prefetch ----
        #pragma unroll 1
        for (int T = 0; T < 7; ++T) {                // t = 3T+s, covers 0..20
            const int t3 = 3 * T;
            L1_MMA(0) L1_PF(0, t3 + 3)
            L1_MMA(1) L1_PF(1, t3 + 4)
            L1_MMA(2) L1_PF(2, t3 + 5)
        }
        // tail: t = 21,22,23,24 (slots 0,1,2,0)
        L1_MMA(0) L1_PF(0, 24)                       // t=21; refill slot0 with t=24
        L1_MMA(1)                                    // t=22
        L1_MMA(2)                                    // t=23

        s16x8 v[3][4], hf[3];
        if (e < NEXP) {                              // layer-2 weight prologue (early)
            #pragma unroll
            for (int p = 0; p < 3; ++p)
                #pragma unroll
                for (int jt = 0; jt < 4; ++jt)
                    v[p][jt] = *(const s16x8*)(w2e + (size_t)jt * 16 * K2P + p * 32);
        }
        L1_MMA(0)                                    // t=24

        if (e < NEXP) {                              // next layer-1 slots (expert e+1)
            const __bf16* w1n = w1e + (size_t)NH1 * K1P;
            #pragma unroll
            for (int p = 0; p < 3; ++p) {
                #pragma unroll
                for (int nt = 0; nt < 4; ++nt)
                    w[p][nt] = *(const s16x8*)(w1n + (size_t)nt * 16 * K1P + p * 32);
                #pragma unroll
                for (int mt = 0; mt < 4; ++mt)
                    a[p][mt] = *(const s16x8*)(xs + (mt * 16 + lr) * XSTRIDE
                                               + p * 32 + lg * 8);
            }
        }

        __syncthreads();   // (1) all waves done reading previous h (drains prefetches)
        // h[m][n] = relu(acc):  (nt,mt,r) -> C[m=mt*16+lr][n=wave*64+nt*16+lg*4+r]
        #pragma unroll
        for (int mt = 0; mt < 4; ++mt)
            #pragma unroll
            for (int nt = 0; nt < 4; ++nt) {
                uint2 wv; __bf16* p = (__bf16*)&wv;
                #pragma unroll
                for (int r = 0; r < 4; ++r)
                    p[r] = (__bf16)fmaxf(acc[nt][mt][r], 0.f);
                *(uint2*)(h + (mt * 16 + lr) * HSTRIDE + wave * 64 + nt * 16 + lg * 4) = wv;
            }
        __syncthreads();   // (2) h ready

        if (e < NEXP) {
            // ================= layer 2: rolled, depth-3 slots =================
            const __bf16* hrow = h + (wave * 16 + lr) * HSTRIDE + lg * 8;
            hf[0] = *(const s16x8*)(hrow);
            hf[1] = *(const s16x8*)(hrow + 32);
            hf[2] = *(const s16x8*)(hrow + 64);

            f32x4 acc2[4];
            #pragma unroll
            for (int jt = 0; jt < 4; ++jt) acc2[jt] = fz;

            #pragma unroll 1
            for (int T = 0; T < 2; ++T) {            // t = 3T+s, covers 0..5
                const int t3 = 3 * T;
                L2_MMA(0) L2_PF(0, t3 + 3)
                L2_MMA(1) L2_PF(1, t3 + 4)
                L2_MMA(2) L2_PF(2, t3 + 5)
            }
            L2_MMA(0) L2_MMA(1) L2_MMA(2)            // t = 6,7,8

            // ---- layer 3: lane owns m = wave*16+lr, j = jt*16+lg*4+r ----
            float part = 0.f;
            const float* w3e = w3s + e * NH2 + lg * 4;
            #pragma unroll
            for (int jt = 0; jt < 4; ++jt) {
                f32x4 w3v = *(const f32x4*)(w3e + jt * 16);
                #pragma unroll
                for (int r = 0; r < 4; ++r)
                    part += fmaxf(acc2[jt][r], 0.f) * w3v[r];
            }
            part += __shfl_xor(part, 16, 64);
            part += __shfl_xor(part, 32, 64);
            if (lane < 16)
                expl[(wave * 16 + lane) * NEXP + e] = part + b3s[e];
        } else {
            // ================= gate: logits -> softmax -> combine =============
            const __bf16* wge = wg2t + (size_t)lr * K2P + lg * 8;
            const __bf16* hrow = h + (wave * 16 + lr) * HSTRIDE + lg * 8;
            s16x8 gf[2], hg[2];
            #pragma unroll
            for (int p = 0; p < 2; ++p) {
                gf[p] = *(const s16x8*)(wge + p * 32);
                hg[p] = *(const s16x8*)(hrow + p * 32);
            }
            f32x4 acc3 = fz;
            #pragma unroll
            for (int t = 0; t < NKS2; ++t) {
                const int ca = t & 1;
                acc3 = __builtin_amdgcn_mfma_f32_16x16x32_bf16(gf[ca], hg[ca], acc3, 0, 0, 0);
                if (t + 2 < NKS2) {
                    gf[ca] = *(const s16x8*)(wge + (t + 2) * 32);
                    hg[ca] = *(const s16x8*)(hrow + (t + 2) * 32);
                }
            }
            // lane: m = wave*16+lr, expert ep = lg*4+r
            const int m = wave * 16 + lr;
            float lv[4], mx = -1e30f;
            #pragma unroll
            for (int r = 0; r < 4; ++r) {
                int ep = lg * 4 + r;
                lv[r] = (ep < NEXP) ? acc3[r] : -1e30f;
                mx = fmaxf(mx, lv[r]);
            }
            mx = fmaxf(mx, __shfl_xor(mx, 16, 64));
            mx = fmaxf(mx, __shfl_xor(mx, 32, 64));
            float p[4], s = 0.f;
            #pragma unroll
            for (int r = 0; r < 4; ++r) {
                int ep = lg * 4 + r;
                p[r] = (ep < NEXP) ? __expf(lv[r] - mx) : 0.f;
                s += p[r];
            }
            s += __shfl_xor(s, 16, 64);
            s += __shfl_xor(s, 32, 64);
            #pragma unroll
            for (int r = 0; r < 4; ++r) {
                int ep = lg * 4 + r;
                if (ep < NEXP) {
                    float g  = p[r] / s;
                    float eo = expl[m * NEXP + ep];
                    size_t o = (size_t)(row0 + m) * NEXP + ep;
                    out[o] = g * eo;                        // output
                    out[(size_t)BTOT * NEXP + o] = g;       // gate_scores
                    out[(size_t)2 * BTOT * NEXP + o] = eo;  // expert_outputs
                }
            }
        }
    }
}

extern "C" void kernel_launch(void* const* d_in, const int* in_sizes, int n_in,
                              void* d_out, int out_size, void* d_ws, size_t ws_size,
                              hipStream_t stream) {
    (void)in_sizes; (void)n_in; (void)out_size; (void)ws_size;
    const float* x   = (const float*)d_in[0];
    const float* W1  = (const float*)d_in[1];
    const float* b1  = (const float*)d_in[2];
    const float* W2  = (const float*)d_in[3];
    const float* b2  = (const float*)d_in[4];
    const float* W3  = (const float*)d_in[5];
    const float* b3  = (const float*)d_in[6];
    const float* Wg1 = (const float*)d_in[7];
    const float* bg1 = (const float*)d_in[8];
    const float* Wg2 = (const float*)d_in[9];
    const float* bg2 = (const float*)d_in[10];

    // ws (bf16): w1t [11][256][800] | w2t [10][64][288] | wg2t [16][288]
    __bf16* w1t  = (__bf16*)d_ws;
    __bf16* w2t  = w1t + (size_t)11 * NH1 * K1P;
    __bf16* wg2t = w2t + (size_t)10 * NH2 * K2P;

    hipFuncSetAttribute((const void*)moe_fused,
                        hipFuncAttributeMaxDynamicSharedMemorySize, LDS_TOTAL);

    prep_w1<<<(11 * 64 * K1P + 255) / 256, 256, 0, stream>>>(W1, b1, Wg1, bg1, w1t);
    prep_w2<<<(10 * 16 * K2P + 255) / 256, 256, 0, stream>>>(W2, b2, w2t);
    prep_wg2<<<(16 * K2P + 255) / 256, 256, 0, stream>>>(Wg2, bg2, wg2t);
    moe_fused<<<BTOT / BM, 256, LDS_TOTAL, stream>>>(x, W3, b3, w1t, w2t, wg2t,
                                                     (float*)d_out);
}

// Round 6
// 349.575 us; speedup vs baseline: 2.5132x; 1.3934x over previous
//
#include <hip/hip_runtime.h>
#include <hip/hip_bf16.h>
#include <stdint.h>

// ---------------- problem dims ----------------
#define BTOT   65536
#define DIN    784
#define K1P    800     // layer-1 K padded: 784 data + bias row @784 + zeros
#define NH1    256
#define NH2    64
#define NEXP   10
#define BM     64
#define NKS1   25      // 800/32
#define NKS2   9       // 288/32 (256 + bias row @256 + zeros)

// ---------------- LDS layout (bytes) ----------------
// All tensors stored in MFMA-fragment order: [blk][kstep][kh][lane][8] bf16,
// so every ds_read_b128 / global wave-load is base + lane*16 (lane-linear).
#define XS_B      102400                   // 2 mb * 25 ks * 2 kh * 1024
#define H_OFF     XS_B
#define H_B       36864                    // 2 mb * 9 ks * 2 kh * 1024
#define EXP2_OFF  (H_OFF + H_B)            // 139264
#define W3S_OFF   (EXP2_OFF + BM * NEXP * 2 * 4)   // 144384
#define B3S_OFF   (W3S_OFF + NEXP * NH2 * 4)       // 146944
#define LDS_TOTAL (B3S_OFF + 64)           // 147008

typedef short s16x8  __attribute__((ext_vector_type(8)));
typedef float f32x4  __attribute__((ext_vector_type(4)));
typedef float f32x16 __attribute__((ext_vector_type(16)));

__device__ __forceinline__ short bf16b(float v) {
    __bf16 b = (__bf16)v;
    return __builtin_bit_cast(short, b);
}

// ---------------- prep: fragment-order weights (bf16, bias folded) ----------
// w1t element (e, nb, ks, kh, lane, j): n = nb*32+(lane&31),
// k = ks*32+kh*16+(lane>>5)*8+j.  e==10 -> gate (Wg1/bg1).
__global__ void prep_w1(const float* __restrict__ W1, const float* __restrict__ b1,
                        const float* __restrict__ Wg1, const float* __restrict__ bg1,
                        __bf16* __restrict__ dst) {
    int t = blockIdx.x * 256 + threadIdx.x;          // < 11*8*25*2*64 = 281600
    int lane = t & 63;
    int rr = t >> 6;
    int kh = rr & 1;
    int ks = (rr >> 1) % 25;
    int nb = ((rr >> 1) / 25) % 8;
    int e  = (rr >> 1) / 200;
    int n  = nb * 32 + (lane & 31);
    int k0 = ks * 32 + kh * 16 + (lane >> 5) * 8;
    const float* src  = (e < NEXP) ? (W1 + (size_t)e * DIN * NH1) : Wg1;
    const float* bias = (e < NEXP) ? (b1 + e * NH1) : bg1;
    s16x8 o;
    #pragma unroll
    for (int j = 0; j < 8; ++j) {
        int k = k0 + j;
        float v = (k < DIN) ? src[(size_t)k * NH1 + n]
                            : ((k == DIN) ? bias[n] : 0.f);
        o[j] = bf16b(v);
    }
    *(s16x8*)((short*)dst + (size_t)t * 8) = o;
}

// w2t element (e, jb, ks, kh, lane, j): n = jb*32+(lane&31), k fragment coords.
__global__ void prep_w2(const float* __restrict__ W2, const float* __restrict__ b2,
                        __bf16* __restrict__ dst) {
    int t = blockIdx.x * 256 + threadIdx.x;          // < 10*2*9*2*64 = 23040
    int lane = t & 63;
    int rr = t >> 6;
    int kh = rr & 1;
    int ks = (rr >> 1) % 9;
    int jb = ((rr >> 1) / 9) & 1;
    int e  = (rr >> 1) / 18;
    int n  = jb * 32 + (lane & 31);
    int k0 = ks * 32 + kh * 16 + (lane >> 5) * 8;
    s16x8 o;
    #pragma unroll
    for (int j = 0; j < 8; ++j) {
        int k = k0 + j;
        float v = (k < NH1) ? W2[((size_t)e * NH1 + k) * NH2 + n]
                            : ((k == NH1) ? b2[e * NH2 + n] : 0.f);
        o[j] = bf16b(v);
    }
    *(s16x8*)((short*)dst + (size_t)t * 8) = o;
}

// wg2t element (ks, kh, lane, j): n = lane&31 (valid <10), k fragment coords.
__global__ void prep_wg2(const float* __restrict__ Wg2, const float* __restrict__ bg2,
                         __bf16* __restrict__ dst) {
    int t = blockIdx.x * 256 + threadIdx.x;
    if (t >= 9 * 2 * 64) return;
    int lane = t & 63;
    int rr = t >> 6;
    int kh = rr & 1;
    int ks = rr >> 1;
    int n  = lane & 31;
    int k0 = ks * 32 + kh * 16 + (lane >> 5) * 8;
    s16x8 o;
    #pragma unroll
    for (int j = 0; j < 8; ++j) {
        int k = k0 + j;
        float v = 0.f;
        if (n < NEXP) {
            if (k < NH1)       v = Wg2[(size_t)k * NEXP + n];
            else if (k == NH1) v = bg2[n];
        }
        o[j] = bf16b(v);
    }
    *(s16x8*)((short*)dst + (size_t)t * 8) = o;
}

// ---- macro bodies (slot index literal -> arrays stay in registers) ----
#define L1A_PF(S, T)                                                          \
    { _Pragma("unroll") for (int mt = 0; mt < 2; ++mt)                        \
        _Pragma("unroll") for (int kh = 0; kh < 2; ++kh)                      \
            a[S][mt][kh] = *(const s16x8*)(pA + ((mt * 25 + (T)) * 2 + kh) * 1024); }

#define L1W_PF(S, T, PW)                                                      \
    { _Pragma("unroll") for (int nt = 0; nt < 2; ++nt)                        \
        _Pragma("unroll") for (int kh = 0; kh < 2; ++kh)                      \
            w[S][nt][kh] = *(const s16x8*)((PW) + nt * 51200 + ((T) * 2 + kh) * 1024); }

#define L1_PF(S, T) L1A_PF(S, T) L1W_PF(S, T, pW)

#define L1_MMA(S)                                                             \
    { _Pragma("unroll") for (int nt = 0; nt < 2; ++nt)                        \
        _Pragma("unroll") for (int mt = 0; mt < 2; ++mt)                      \
            _Pragma("unroll") for (int kh = 0; kh < 2; ++kh)                  \
                acc[nt][mt] = __builtin_amdgcn_mfma_f32_32x32x16_bf16(        \
                    w[S][nt][kh], a[S][mt][kh], acc[nt][mt], 0, 0, 0); }

#define L2_PF(S, T)                                                           \
    { _Pragma("unroll") for (int kh = 0; kh < 2; ++kh) {                      \
        hfr[S][kh] = *(const s16x8*)(pH + ((T) * 2 + kh) * 1024);             \
        v2[S][kh]  = *(const s16x8*)(pV + ((T) * 2 + kh) * 1024); } }

#define L2_MMA(S)                                                             \
    { _Pragma("unroll") for (int kh = 0; kh < 2; ++kh)                        \
        acc2 = __builtin_amdgcn_mfma_f32_32x32x16_bf16(                       \
            v2[S][kh], hfr[S][kh], acc2, 0, 0, 0); }

// ---------------- fused MoE kernel ----------------
// 4 waves, 64 rows/block. 32x32x16 MFMA, operands swapped (A=weights, B=x):
// D[n][m]: m = lane&31, n_local = (reg&3) + 8*(reg>>2) + 4*(lane>>5).
// Wave tile layer-1: 64m x 64n (nt=2 x mt=2); weights global->reg via 3-deep
// rotating slots, all loads lane-linear contiguous 1KB.
__global__ void __launch_bounds__(256, 1)
moe_fused(const float* __restrict__ x, const float* __restrict__ W3,
          const float* __restrict__ b3, const __bf16* __restrict__ w1t,
          const __bf16* __restrict__ w2t, const __bf16* __restrict__ wg2t,
          float* __restrict__ out)
{
    extern __shared__ char lds[];
    char*  xsb   = lds;
    char*  hb    = lds + H_OFF;
    float* expl2 = (float*)(lds + EXP2_OFF);   // [64 m][10 e][2 jb]
    float* w3s   = (float*)(lds + W3S_OFF);
    float* b3s   = (float*)(lds + B3S_OFF);

    const int tid  = threadIdx.x;
    const int lane = tid & 63;
    const int wave = tid >> 6;
    const int rl   = lane & 31;
    const int hi   = lane >> 5;
    const int row0 = blockIdx.x * BM;
    const char* w1c = (const char*)w1t;

    // per-lane fragment base pointers (byte)
    const char* pA = xsb + lane * 16;
    const char* pW = w1c + (size_t)(wave * 2) * 51200 + lane * 16;  // e=0

    // ---- issue expert-0 weight slots FIRST (hide under x staging) ----
    s16x8 w[3][2][2], a[3][2][2];
    L1W_PF(0, 0, pW) L1W_PF(1, 1, pW) L1W_PF(2, 2, pW)

    // ---- stage x tile fp32 -> bf16 fragment layout ----
    {
        const float* xg = x + (size_t)row0 * DIN;
        #pragma unroll 4
        for (int i = 0; i < 49; ++i) {               // 49*256 == 64*196
            int idx = tid + i * 256;
            int r = idx / 196, c = (idx % 196) * 4;
            float4 v = *(const float4*)(xg + (size_t)r * DIN + c);
            int ks = c >> 5, kin = c & 31;
            int kh = kin >> 4, hw = (kin >> 3) & 1, j = c & 7;
            uint2 wv; short* p = (short*)&wv;
            p[0] = bf16b(v.x); p[1] = bf16b(v.y);
            p[2] = bf16b(v.z); p[3] = bf16b(v.w);
            *(uint2*)(xsb + ((((r >> 5) * 25 + ks) * 2 + kh) * 2 + hw) * 512
                          + (r & 31) * 16 + j * 2) = wv;
        }
        // x pad: k = 784 (bias 1.0) .. 799 (zeros): ks=24, kh=1
        for (int i = tid; i < 64 * 4; i += 256) {
            int r = i >> 2, g = i & 3;
            int hw = g >> 1, j0 = (g & 1) * 4;
            uint2 wv = {0u, 0u};
            if (g == 0) ((short*)&wv)[0] = bf16b(1.f);
            *(uint2*)(xsb + ((((r >> 5) * 25 + 24) * 2 + 1) * 2 + hw) * 512
                          + (r & 31) * 16 + j0 * 2) = wv;
        }
        // h pad block ks2=8 (constant across experts): 1.0 at k=256, else 0
        for (int i = tid; i < 2 * 1024; i += 256) {
            int mb = i >> 10, q = i & 1023;
            short v = (q < 256 && (q & 7) == 0) ? bf16b(1.f) : (short)0;
            *(short*)(hb + (mb * 9 + 8) * 2048 + q * 2) = v;
        }
        for (int i = tid; i < NEXP * NH2; i += 256) w3s[i] = W3[i];
        if (tid < NEXP) b3s[tid] = b3[tid];
    }
    __syncthreads();

    // a-slot prologue for expert 0
    L1A_PF(0, 0) L1A_PF(1, 1) L1A_PF(2, 2)

    #pragma unroll 1
    for (int e = 0; e <= NEXP; ++e) {
        const char* pWe = w1c + (size_t)(e * 8 + wave * 2) * 51200 + lane * 16;
        #define pW pWe

        f32x16 acc[2][2];
        #pragma unroll
        for (int nt = 0; nt < 2; ++nt)
            #pragma unroll
            for (int mt = 0; mt < 2; ++mt)
                #pragma unroll
                for (int q = 0; q < 16; ++q) acc[nt][mt][q] = 0.f;

        // ---- K loop: rolled, 3 slot-bodies/iter, depth-3 prefetch ----
        #pragma unroll 1
        for (int T = 0; T < 7; ++T) {                // t = 3T+s, covers 0..20
            const int t3 = 3 * T;
            L1_MMA(0) L1_PF(0, t3 + 3)
            L1_MMA(1) L1_PF(1, t3 + 4)
            L1_MMA(2) L1_PF(2, t3 + 5)
        }
        L1_MMA(0) L1_PF(0, 24)                       // t=21
        L1_MMA(1)                                    // t=22
        L1_MMA(2)                                    // t=23
        #undef pW

        // layer-2 weight slots (early: latency hides under epilogue)
        const int mb2 = wave >> 1, jb = wave & 1;
        const char* pH = hb + mb2 * 18432 + lane * 16;
        const char* pV = (const char*)w2t + (size_t)(e * 2 + jb) * 18432 + lane * 16;
        s16x8 v2[3][2], hfr[3][2];
        if (e < NEXP) {
            #pragma unroll
            for (int p = 0; p < 3; ++p)
                #pragma unroll
                for (int kh = 0; kh < 2; ++kh)
                    v2[p][kh] = *(const s16x8*)(pV + (p * 2 + kh) * 1024);
        }
        L1_MMA(0)                                    // t=24

        // refill slots for expert e+1 (w from global, a from LDS)
        if (e < NEXP) {
            const char* pWn = pWe + 8 * 51200;
            L1W_PF(0, 0, pWn) L1W_PF(1, 1, pWn) L1W_PF(2, 2, pWn)
            L1A_PF(0, 0) L1A_PF(1, 1) L1A_PF(2, 2)
        }

        __syncthreads();   // (1) all waves done reading previous h
        // h-write in fragment layout: lane m = mt*32+rl; reg q*4+r2 ->
        // n_local = r2 + 8q + 4hi -> (kh2=q>>1, hi2=q&1, j=r2+4hi)
        #pragma unroll
        for (int mt = 0; mt < 2; ++mt)
            #pragma unroll
            for (int nt = 0; nt < 2; ++nt) {
                const int ks2 = wave * 2 + nt;
                #pragma unroll
                for (int q = 0; q < 4; ++q) {
                    uint2 wv; short* p = (short*)&wv;
                    #pragma unroll
                    for (int r2 = 0; r2 < 4; ++r2)
                        p[r2] = bf16b(fmaxf(acc[nt][mt][q * 4 + r2], 0.f));
                    *(uint2*)(hb + ((mt * 9 + ks2) * 2 + (q >> 1)) * 1024
                                 + (q & 1) * 512 + rl * 16 + hi * 8) = wv;
                }
            }
        __syncthreads();   // (2) h ready

        if (e < NEXP) {
            // ================= layer 2: 9 steps, depth-3 slots =============
            f32x16 acc2;
            #pragma unroll
            for (int q = 0; q < 16; ++q) acc2[q] = 0.f;
            #pragma unroll
            for (int kh = 0; kh < 2; ++kh)
                hfr[0][kh] = *(const s16x8*)(pH + (0 * 2 + kh) * 1024);
            #pragma unroll
            for (int kh = 0; kh < 2; ++kh)
                hfr[1][kh] = *(const s16x8*)(pH + (1 * 2 + kh) * 1024);
            #pragma unroll
            for (int kh = 0; kh < 2; ++kh)
                hfr[2][kh] = *(const s16x8*)(pH + (2 * 2 + kh) * 1024);

            #pragma unroll 1
            for (int T = 0; T < 2; ++T) {            // t = 3T+s, covers 0..5
                const int t3 = 3 * T;
                L2_MMA(0) L2_PF(0, t3 + 3)
                L2_MMA(1) L2_PF(1, t3 + 4)
                L2_MMA(2) L2_PF(2, t3 + 5)
            }
            L2_MMA(0) L2_MMA(1) L2_MMA(2)            // t = 6,7,8

            // ---- layer 3: lane m = mb2*32+rl; j = jb*32 + r2+8q+4hi ----
            // NOTE: b3 is added ONCE at the gate-combine (each jb half
            // stores only its raw partial sum here — round-5 bug was
            // adding b3 in both halves).
            float part = 0.f;
            const float* w3p = w3s + e * NH2 + jb * 32 + 4 * hi;
            #pragma unroll
            for (int q = 0; q < 4; ++q) {
                f32x4 w3v = *(const f32x4*)(w3p + 8 * q);
                #pragma unroll
                for (int r2 = 0; r2 < 4; ++r2)
                    part += fmaxf(acc2[q * 4 + r2], 0.f) * w3v[r2];
            }
            part += __shfl_xor(part, 32, 64);
            if (hi == 0)
                expl2[(mb2 * 32 + rl) * (NEXP * 2) + e * 2 + jb] = part;
        } else if (wave < 2) {
            // ================= gate: logits -> softmax -> combine ==========
            const int mbg = wave;
            const char* pHg = hb + mbg * 18432 + lane * 16;
            const char* pG  = (const char*)wg2t + lane * 16;
            f32x16 acc3;
            #pragma unroll
            for (int q = 0; q < 16; ++q) acc3[q] = 0.f;
            {
                s16x8 v2[3][2], hfr[3][2];
                const char* pH = pHg;
                const char* pV = pG;
                L2_PF(0, 0) L2_PF(1, 1) L2_PF(2, 2)
                #define acc2 acc3
                #pragma unroll 1
                for (int T = 0; T < 2; ++T) {
                    const int t3 = 3 * T;
                    L2_MMA(0) L2_PF(0, t3 + 3)
                    L2_MMA(1) L2_PF(1, t3 + 4)
                    L2_MMA(2) L2_PF(2, t3 + 5)
                }
                L2_MMA(0) L2_MMA(1) L2_MMA(2)
                #undef acc2
            }
            // lane m = mbg*32+rl; reg q*4+r2 -> j = r2+8q+4hi (valid <10)
            const int m = mbg * 32 + rl;
            float mx = -1e30f;
            float lv[16];
            #pragma unroll
            for (int q = 0; q < 4; ++q)
                #pragma unroll
                for (int r2 = 0; r2 < 4; ++r2) {
                    int j = r2 + 8 * q + 4 * hi;
                    int rg = q * 4 + r2;
                    lv[rg] = (j < NEXP) ? acc3[rg] : -1e30f;
                    mx = fmaxf(mx, lv[rg]);
                }
            mx = fmaxf(mx, __shfl_xor(mx, 32, 64));
            float s = 0.f;
            float pv[16];
            #pragma unroll
            for (int rg = 0; rg < 16; ++rg) {
                pv[rg] = (lv[rg] > -1e29f) ? __expf(lv[rg] - mx) : 0.f;
                s += pv[rg];
            }
            s += __shfl_xor(s, 32, 64);
            const float inv = 1.f / s;
            #pragma unroll
            for (int q = 0; q < 4; ++q)
                #pragma unroll
                for (int r2 = 0; r2 < 4; ++r2) {
                    int j = r2 + 8 * q + 4 * hi;
                    if (j < NEXP) {
                        float g  = pv[q * 4 + r2] * inv;
                        float eo = expl2[m * (NEXP * 2) + j * 2]
                                 + expl2[m * (NEXP * 2) + j * 2 + 1]
                                 + b3s[j];
                        size_t o = (size_t)(row0 + m) * NEXP + j;
                        out[o] = g * eo;
                        out[(size_t)BTOT * NEXP + o] = g;
                        out[(size_t)2 * BTOT * NEXP + o] = eo;
                    }
                }
        }
    }
}

extern "C" void kernel_launch(void* const* d_in, const int* in_sizes, int n_in,
                              void* d_out, int out_size, void* d_ws, size_t ws_size,
                              hipStream_t stream) {
    (void)in_sizes; (void)n_in; (void)out_size; (void)ws_size;
    const float* x   = (const float*)d_in[0];
    const float* W1  = (const float*)d_in[1];
    const float* b1  = (const float*)d_in[2];
    const float* W2  = (const float*)d_in[3];
    const float* b2  = (const float*)d_in[4];
    const float* W3  = (const float*)d_in[5];
    const float* b3  = (const float*)d_in[6];
    const float* Wg1 = (const float*)d_in[7];
    const float* bg1 = (const float*)d_in[8];
    const float* Wg2 = (const float*)d_in[9];
    const float* bg2 = (const float*)d_in[10];

    // ws (bf16, fragment order): w1t 11*8*25*2*64*8 | w2t 10*2*9*2*64*8 | wg2t 9*2*64*8
    __bf16* w1t  = (__bf16*)d_ws;
    __bf16* w2t  = w1t + (size_t)11 * 8 * 25 * 2 * 64 * 8;
    __bf16* wg2t = w2t + (size_t)10 * 2 * 9 * 2 * 64 * 8;

    hipFuncSetAttribute((const void*)moe_fused,
                        hipFuncAttributeMaxDynamicSharedMemorySize, LDS_TOTAL);

    prep_w1<<<1100, 256, 0, stream>>>(W1, b1, Wg1, bg1, w1t);
    prep_w2<<<90, 256, 0, stream>>>(W2, b2, w2t);
    prep_wg2<<<5, 256, 0, stream>>>(Wg2, bg2, wg2t);
    moe_fused<<<BTOT / BM, 256, LDS_TOTAL, stream>>>(x, W3, b3, w1t, w2t, wg2t,
                                                     (float*)d_out);
}